// Round 7
// baseline (166.902 us; speedup 1.0000x reference)
//
#include <hip/hip_runtime.h>
#include <hip/hip_bf16.h>

#define NN 20000
#define EE 160000
#define HH 32
#define MIDD 32

typedef _Float16 f16x4 __attribute__((ext_vector_type(4)));
typedef _Float16 f16x8 __attribute__((ext_vector_type(8)));
typedef float f32x4 __attribute__((ext_vector_type(4)));

__device__ __forceinline__ float silu_f(float v) {
    return __fdividef(v, 1.0f + __expf(-v));
}

// ---------------- prep kernels ----------------

__global__ void count_kernel(const int* __restrict__ ei, int* __restrict__ cnt) {
    int e = blockIdx.x * 256 + threadIdx.x;
    if (e < EE) atomicAdd(&cnt[ei[EE + e]], 1);
}

// writes off, a mutable copy cur (=off), and invc — scatter atomics hit cur.
__global__ void scan_kernel(const int* __restrict__ cnt, int* __restrict__ off,
                            int* __restrict__ cur, float* __restrict__ invc) {
    __shared__ int tot[1024];
    const int t = threadIdx.x;
    const int CH = 20;
    int base = t * CH;
    int loc[CH];
    int s = 0;
    #pragma unroll
    for (int r = 0; r < CH; ++r) {
        int idx = base + r;
        int c = (idx < NN) ? cnt[idx] : 0;
        loc[r] = s;
        s += c;
    }
    tot[t] = s;
    __syncthreads();
    for (int d = 1; d < 1024; d <<= 1) {
        int u = (t >= d) ? tot[t - d] : 0;
        __syncthreads();
        tot[t] += u;
        __syncthreads();
    }
    int basesum = (t == 0) ? 0 : tot[t - 1];
    #pragma unroll
    for (int r = 0; r < CH; ++r) {
        int idx = base + r;
        if (idx < NN) {
            int o = basesum + loc[r];
            off[idx] = o;
            cur[idx] = o;
            invc[idx] = 1.0f / fmaxf((float)cnt[idx], 1.0f);
        }
    }
    if (t == 0) off[NN] = EE;
}

__global__ void scatter_kernel(const int* __restrict__ ei, const float* __restrict__ ewt,
                               int* __restrict__ cur,
                               int* __restrict__ ssrc, float* __restrict__ sew) {
    int e = blockIdx.x * 256 + threadIdx.x;
    if (e < EE) {
        int d = ei[EE + e];
        int pos = atomicAdd(&cur[d], 1);
        ssrc[pos] = ei[e];
        sew[pos] = ewt[e];
    }
}

// Wt[o][k] fp16 transposed weights. S-part k = 32*i + m  ->  w2[m*(CIN*32)+i*32+o];
// tail1 k = 32*CIN + t -> b2[t*32+o]; tail2 k = 33*CIN + t -> root[t*32+o].
__global__ void build_wt(const float* __restrict__ w2a, const float* __restrict__ b2a,
                         const float* __restrict__ ra,
                         const float* __restrict__ w2b, const float* __restrict__ b2b,
                         const float* __restrict__ rb,
                         _Float16* __restrict__ Wt1, _Float16* __restrict__ Wt2) {
    int idx = blockIdx.x * 256 + threadIdx.x;
    if (idx < 17408) {                       // 32 * 544 (CIN=16)
        int o = idx / 544, k = idx % 544;
        float v;
        if (k < 512) {
            int m = k & 31, i = k >> 5;
            v = w2a[m * 512 + i * 32 + o];
        } else if (k < 528) {
            v = b2a[(k - 512) * 32 + o];
        } else {
            v = ra[(k - 528) * 32 + o];
        }
        Wt1[o * 544 + k] = (_Float16)v;
    } else if (idx < 52224) {                // + 32 * 1088 (CIN=32)
        int j = idx - 17408;
        int o = j / 1088, k = j % 1088;
        float v;
        if (k < 1024) {
            int m = k & 31, i = k >> 5;
            v = w2b[m * 1024 + i * 32 + o];
        } else if (k < 1056) {
            v = b2b[(k - 1024) * 32 + o];
        } else {
            v = rb[(k - 1056) * 32 + o];
        }
        Wt2[o * 1088 + k] = (_Float16)v;
    }
}

// ---------------- fused layer kernel: edges -> LDS F -> MFMA gemm ----------
// Block = 512 threads (8 waves), 16 nodes. Phase A: wave w builds F rows for
// nodes n0+2w, n0+2w+1 (zero-shuffle register pipeline; lane owns m=lane&31,
// i-range [(lane>>5)*JS, +JS)), writes rows into LDS Fl[node][k] fp16,
// LDK=K+4. Phase B: 8 waves split K-steps; A-frags from LDS, B-frags from
// L2-resident Wt; waves 1-7 dump partials to red[]; wave 0 reduces + epilogue.
// 49.3 KB LDS (CIN=32) -> 3 blocks/CU = 24 waves/CU for gather-latency hiding.

template <int CIN, bool DECODE>
__global__ __launch_bounds__(512, 6) void fused_layer(
    const float* __restrict__ xin, const int* __restrict__ ssrc,
    const float* __restrict__ sew, const int* __restrict__ off,
    const float* __restrict__ invc, const float* __restrict__ w1,
    const float* __restrict__ b1, const _Float16* __restrict__ Wt,
    const float* __restrict__ bias, float* __restrict__ outp,
    const float* __restrict__ dw, const float* __restrict__ db) {
    constexpr int K = 34 * CIN;              // 544 or 1088
    constexpr int LDK = K + 4;
    constexpr int JS = (32 * CIN) / 64;      // 8 or 16
    constexpr int NQ = JS / 4;               // 2 or 4
    constexpr int steps = K / 32;            // 17 or 34

    __shared__ _Float16 Fl[16 * LDK];
    __shared__ float red[7 * 512];

    const int t = threadIdx.x;
    const int n0 = blockIdx.x * 16;
    const int lane = t & 63, w = t >> 6;     // 8 waves

    // ---- Phase A: 2 nodes per wave ----
    {
        const int m = lane & 31;
        const int ihalf = (lane >> 5) * JS;
        const int i0 = lane & (CIN - 1);
        const float w1v = w1[m];
        const float b1v = b1[m];

        for (int c = 0; c < 2; ++c) {
            const int nsub = w * 2 + c;
            const int d = n0 + nsub;
            float Sacc[JS];
            #pragma unroll
            for (int j = 0; j < JS; ++j) Sacc[j] = 0.f;
            float S0 = 0.f;

            const int e0 = off[d], e1 = off[d + 1];
            const float iv = invc[d];

            #pragma unroll 2
            for (int e = e0; e < e1; ++e) {
                const int sn = ssrc[e];
                const float ew = sew[e];
                const float4* xr = (const float4*)(xin + (size_t)sn * CIN) + (ihalf >> 2);
                float4 xv[NQ];
                #pragma unroll
                for (int q = 0; q < NQ; ++q) xv[q] = xr[q];
                const float x0 = xin[(size_t)sn * CIN + i0];
                const float hv = silu_f(fmaf(ew, w1v, b1v));
                #pragma unroll
                for (int q = 0; q < NQ; ++q) {
                    Sacc[4 * q + 0] = fmaf(hv, xv[q].x, Sacc[4 * q + 0]);
                    Sacc[4 * q + 1] = fmaf(hv, xv[q].y, Sacc[4 * q + 1]);
                    Sacc[4 * q + 2] = fmaf(hv, xv[q].z, Sacc[4 * q + 2]);
                    Sacc[4 * q + 3] = fmaf(hv, xv[q].w, Sacc[4 * q + 3]);
                }
                S0 += x0;
            }

            _Float16* Fr = Fl + (size_t)nsub * LDK;
            #pragma unroll
            for (int j = 0; j < JS; ++j)
                Fr[(ihalf + j) * 32 + m] = (_Float16)(Sacc[j] * iv);
            if (lane < CIN)
                Fr[32 * CIN + lane] = (_Float16)(S0 * iv);
            else if (lane < 2 * CIN)
                Fr[32 * CIN + lane] = (_Float16)xin[(size_t)d * CIN + (lane - CIN)];
        }
    }
    __syncthreads();

    // ---- Phase B: 8-way K-split MFMA ----
    const int o16 = lane & 15, g = lane >> 4;

    const _Float16* Arow = Fl + (size_t)o16 * LDK + g * 4;
    const _Float16* B0 = Wt + (size_t)o16 * K + g * 4;
    const _Float16* B1 = Wt + (size_t)(o16 + 16) * K + g * 4;

    f32x4 acc0 = {0.f, 0.f, 0.f, 0.f};
    f32x4 acc1 = {0.f, 0.f, 0.f, 0.f};

    const int sb = (steps * w) >> 3;
    const int se = (steps * (w + 1)) >> 3;
    #pragma unroll 2
    for (int s = sb; s < se; ++s) {
        const int k0 = s * 32;
        f16x4 alo = *(const f16x4*)(Arow + k0);
        f16x4 ahi = *(const f16x4*)(Arow + k0 + 16);
        f16x4 b0l = *(const f16x4*)(B0 + k0);
        f16x4 b0h = *(const f16x4*)(B0 + k0 + 16);
        f16x4 b1l = *(const f16x4*)(B1 + k0);
        f16x4 b1h = *(const f16x4*)(B1 + k0 + 16);
        f16x8 a, bb0, bb1;
        #pragma unroll
        for (int j = 0; j < 4; ++j) {
            a[j] = alo[j];  a[j + 4] = ahi[j];
            bb0[j] = b0l[j]; bb0[j + 4] = b0h[j];
            bb1[j] = b1l[j]; bb1[j + 4] = b1h[j];
        }
        acc0 = __builtin_amdgcn_mfma_f32_16x16x32_f16(a, bb0, acc0, 0, 0, 0);
        acc1 = __builtin_amdgcn_mfma_f32_16x16x32_f16(a, bb1, acc1, 0, 0, 0);
    }

    if (w > 0) {
        float* rw = red + (w - 1) * 512;
        #pragma unroll
        for (int r = 0; r < 4; ++r) {
            rw[(g * 4 + r) * 32 + o16]      = acc0[r];
            rw[(g * 4 + r) * 32 + 16 + o16] = acc1[r];
        }
    }
    __syncthreads();
    if (w == 0) {
        #pragma unroll
        for (int r = 0; r < 4; ++r) {
            const int ro = (g * 4 + r) * 32 + o16;
            #pragma unroll
            for (int p = 0; p < 7; ++p) {
                acc0[r] += red[p * 512 + ro];
                acc1[r] += red[p * 512 + ro + 16];
            }
        }
        const float bb0 = bias[o16], bb1 = bias[o16 + 16];
        const int nrow = n0 + g * 4;
        if (!DECODE) {
            #pragma unroll
            for (int r = 0; r < 4; ++r) {
                outp[(size_t)(nrow + r) * 32 + o16]      = silu_f(acc0[r] + bb0);
                outp[(size_t)(nrow + r) * 32 + 16 + o16] = silu_f(acc1[r] + bb1);
            }
        } else {
            const float w0 = dw[o16], w1v = dw[o16 + 16];
            const float dbv = db[0];
            #pragma unroll
            for (int r = 0; r < 4; ++r) {
                float p = silu_f(acc0[r] + bb0) * w0 + silu_f(acc1[r] + bb1) * w1v;
                p += __shfl_xor(p, 1);
                p += __shfl_xor(p, 2);
                p += __shfl_xor(p, 4);
                p += __shfl_xor(p, 8);
                if (o16 == 0) outp[nrow + r] = p + dbv;
            }
        }
    }
}

// ---------------- launch ----------------

extern "C" void kernel_launch(void* const* d_in, const int* in_sizes, int n_in,
                              void* d_out, int out_size, void* d_ws, size_t ws_size,
                              hipStream_t stream) {
    const float* x      = (const float*)d_in[0];
    const int*   ei     = (const int*)d_in[1];
    const float* ew     = (const float*)d_in[2];
    const float* en1_w1 = (const float*)d_in[3];
    const float* en1_b1 = (const float*)d_in[4];
    const float* en1_w2 = (const float*)d_in[5];
    const float* en1_b2 = (const float*)d_in[6];
    const float* root1  = (const float*)d_in[7];
    const float* bias1  = (const float*)d_in[8];
    const float* en2_w1 = (const float*)d_in[9];
    const float* en2_b1 = (const float*)d_in[10];
    const float* en2_w2 = (const float*)d_in[11];
    const float* en2_b2 = (const float*)d_in[12];
    const float* root2  = (const float*)d_in[13];
    const float* bias2  = (const float*)d_in[14];
    const float* dec_w  = (const float*)d_in[15];
    const float* dec_b  = (const float*)d_in[16];
    float* out = (float*)d_out;
    (void)in_sizes; (void)n_in; (void)out_size; (void)ws_size;

    char* wp = (char*)d_ws;
    auto alloc = [&](size_t bytes) {
        char* p = wp;
        wp += (bytes + 255) & ~(size_t)255;
        return p;
    };
    int*      cnt  = (int*)alloc((size_t)NN * 4);
    int*      off  = (int*)alloc((size_t)(NN + 1) * 4);
    int*      cur  = (int*)alloc((size_t)NN * 4);
    float*    invc = (float*)alloc((size_t)NN * 4);
    int*      ssrc = (int*)alloc((size_t)EE * 4);
    float*    sew  = (float*)alloc((size_t)EE * 4);
    float*    h1   = (float*)alloc((size_t)NN * 32 * 4);
    _Float16* Wt1  = (_Float16*)alloc((size_t)17408 * 2);
    _Float16* Wt2  = (_Float16*)alloc((size_t)34816 * 2);

    hipMemsetAsync(cnt, 0, (size_t)NN * 4, stream);

    count_kernel<<<(EE + 255) / 256, 256, 0, stream>>>(ei, cnt);
    scan_kernel<<<1, 1024, 0, stream>>>(cnt, off, cur, invc);
    scatter_kernel<<<(EE + 255) / 256, 256, 0, stream>>>(ei, ew, cur, ssrc, sew);
    build_wt<<<(52224 + 255) / 256, 256, 0, stream>>>(en1_w2, en1_b2, root1,
                                                      en2_w2, en2_b2, root2, Wt1, Wt2);

    fused_layer<16, false><<<NN / 16, 512, 0, stream>>>(
        x, ssrc, sew, off, invc, en1_w1, en1_b1, Wt1, bias1, h1, nullptr, nullptr);
    fused_layer<32, true><<<NN / 16, 512, 0, stream>>>(
        h1, ssrc, sew, off, invc, en2_w1, en2_b1, Wt2, bias2, out, dec_w, dec_b);
}

// Round 8
// 166.637 us; speedup vs baseline: 1.0016x; 1.0016x over previous
//
#include <hip/hip_runtime.h>
#include <hip/hip_bf16.h>

#define NN 20000
#define EE 160000
#define HH 32
#define MIDD 32

typedef _Float16 f16x4 __attribute__((ext_vector_type(4)));
typedef _Float16 f16x8 __attribute__((ext_vector_type(8)));
typedef float f32x4 __attribute__((ext_vector_type(4)));

__device__ __forceinline__ float silu_f(float v) {
    return __fdividef(v, 1.0f + __expf(-v));
}

// ---------------- prep kernels ----------------

__global__ void count_kernel(const int* __restrict__ ei, int* __restrict__ cnt) {
    int e = blockIdx.x * 256 + threadIdx.x;
    if (e < EE) atomicAdd(&cnt[ei[EE + e]], 1);
}

// writes off, a mutable copy cur (=off), and invc — scatter atomics hit cur.
__global__ void scan_kernel(const int* __restrict__ cnt, int* __restrict__ off,
                            int* __restrict__ cur, float* __restrict__ invc) {
    __shared__ int tot[1024];
    const int t = threadIdx.x;
    const int CH = 20;
    int base = t * CH;
    int loc[CH];
    int s = 0;
    #pragma unroll
    for (int r = 0; r < CH; ++r) {
        int idx = base + r;
        int c = (idx < NN) ? cnt[idx] : 0;
        loc[r] = s;
        s += c;
    }
    tot[t] = s;
    __syncthreads();
    for (int d = 1; d < 1024; d <<= 1) {
        int u = (t >= d) ? tot[t - d] : 0;
        __syncthreads();
        tot[t] += u;
        __syncthreads();
    }
    int basesum = (t == 0) ? 0 : tot[t - 1];
    #pragma unroll
    for (int r = 0; r < CH; ++r) {
        int idx = base + r;
        if (idx < NN) {
            int o = basesum + loc[r];
            off[idx] = o;
            cur[idx] = o;
            invc[idx] = 1.0f / fmaxf((float)cnt[idx], 1.0f);
        }
    }
    if (t == 0) off[NN] = EE;
}

__global__ void scatter_kernel(const int* __restrict__ ei, const float* __restrict__ ewt,
                               int* __restrict__ cur,
                               int* __restrict__ ssrc, float* __restrict__ sew) {
    int e = blockIdx.x * 256 + threadIdx.x;
    if (e < EE) {
        int d = ei[EE + e];
        int pos = atomicAdd(&cur[d], 1);
        ssrc[pos] = ei[e];
        sew[pos] = ewt[e];
    }
}

// Wt[o][k] fp16 transposed weights. S-part k = 32*i + m  ->  w2[m*(CIN*32)+i*32+o];
// tail1 k = 32*CIN + t -> b2[t*32+o]; tail2 k = 33*CIN + t -> root[t*32+o].
__global__ void build_wt(const float* __restrict__ w2a, const float* __restrict__ b2a,
                         const float* __restrict__ ra,
                         const float* __restrict__ w2b, const float* __restrict__ b2b,
                         const float* __restrict__ rb,
                         _Float16* __restrict__ Wt1, _Float16* __restrict__ Wt2) {
    int idx = blockIdx.x * 256 + threadIdx.x;
    if (idx < 17408) {                       // 32 * 544 (CIN=16)
        int o = idx / 544, k = idx % 544;
        float v;
        if (k < 512) {
            int m = k & 31, i = k >> 5;
            v = w2a[m * 512 + i * 32 + o];
        } else if (k < 528) {
            v = b2a[(k - 512) * 32 + o];
        } else {
            v = ra[(k - 528) * 32 + o];
        }
        Wt1[o * 544 + k] = (_Float16)v;
    } else if (idx < 52224) {                // + 32 * 1088 (CIN=32)
        int j = idx - 17408;
        int o = j / 1088, k = j % 1088;
        float v;
        if (k < 1024) {
            int m = k & 31, i = k >> 5;
            v = w2b[m * 1024 + i * 32 + o];
        } else if (k < 1056) {
            v = b2b[(k - 1024) * 32 + o];
        } else {
            v = rb[(k - 1056) * 32 + o];
        }
        Wt2[o * 1088 + k] = (_Float16)v;
    }
}

// ---------------- fused layer kernel: edges -> LDS F -> MFMA gemm ----------
// Block = 512 threads (8 waves), 16 nodes; wave w owns nodes n0+2w..+1.
// Phase A with EXPLICIT edge batching (B=8/4): all (sn,ew) of a batch load
// independently, then all x-row gathers issue together (B*(NQ+1) loads in
// flight), then compute. Tail = clamped index + validity mask (no divergence).
// Phase B: verified 8-way K-split MFMA; waves 1-7 dump partials; wave 0
// reduces + epilogue.

template <int CIN, bool DECODE>
__global__ __launch_bounds__(512, 4) void fused_layer(
    const float* __restrict__ xin, const int* __restrict__ ssrc,
    const float* __restrict__ sew, const int* __restrict__ off,
    const float* __restrict__ invc, const float* __restrict__ w1,
    const float* __restrict__ b1, const _Float16* __restrict__ Wt,
    const float* __restrict__ bias, float* __restrict__ outp,
    const float* __restrict__ dw, const float* __restrict__ db) {
    constexpr int K = 34 * CIN;              // 544 or 1088
    constexpr int LDK = K + 4;
    constexpr int JS = (32 * CIN) / 64;      // 8 or 16
    constexpr int NQ = JS / 4;               // 2 or 4
    constexpr int steps = K / 32;            // 17 or 34
    constexpr int B = (CIN == 16) ? 8 : 4;   // edge batch size

    __shared__ _Float16 Fl[16 * LDK];
    __shared__ float red[7 * 512];

    const int t = threadIdx.x;
    const int n0 = blockIdx.x * 16;
    const int lane = t & 63, w = t >> 6;     // 8 waves

    // ---- Phase A: 2 nodes per wave, batched gathers ----
    {
        const int m = lane & 31;
        const int ihalf = (lane >> 5) * JS;
        const int i0 = lane & (CIN - 1);
        const float w1v = w1[m];
        const float b1v = b1[m];

        for (int c = 0; c < 2; ++c) {
            const int nsub = w * 2 + c;
            const int d = n0 + nsub;
            float Sacc[JS];
            #pragma unroll
            for (int j = 0; j < JS; ++j) Sacc[j] = 0.f;
            float S0 = 0.f;

            const int e0 = off[d], e1 = off[d + 1];
            const float iv = invc[d];

            for (int b0 = e0; b0 < e1; b0 += B) {
                // stage 1: batch (sn, ew) — independent loads
                int sn[B]; float ww[B];
                #pragma unroll
                for (int u = 0; u < B; ++u) {
                    const int e = b0 + u;
                    const int ec = (e < e1) ? e : (e1 - 1);
                    sn[u] = ssrc[ec];
                    ww[u] = sew[ec];
                }
                // stage 2: batch x-row gathers — all independent, in flight together
                float4 xv[B][NQ]; float x0[B];
                #pragma unroll
                for (int u = 0; u < B; ++u) {
                    const float* xrow = xin + (size_t)sn[u] * CIN;
                    const float4* xr = (const float4*)xrow + (ihalf >> 2);
                    #pragma unroll
                    for (int q = 0; q < NQ; ++q) xv[u][q] = xr[q];
                    x0[u] = xrow[i0];
                }
                // stage 3: compute
                #pragma unroll
                for (int u = 0; u < B; ++u) {
                    const float valid = (b0 + u < e1) ? 1.f : 0.f;
                    const float hv = valid * silu_f(fmaf(ww[u], w1v, b1v));
                    #pragma unroll
                    for (int q = 0; q < NQ; ++q) {
                        Sacc[4 * q + 0] = fmaf(hv, xv[u][q].x, Sacc[4 * q + 0]);
                        Sacc[4 * q + 1] = fmaf(hv, xv[u][q].y, Sacc[4 * q + 1]);
                        Sacc[4 * q + 2] = fmaf(hv, xv[u][q].z, Sacc[4 * q + 2]);
                        Sacc[4 * q + 3] = fmaf(hv, xv[u][q].w, Sacc[4 * q + 3]);
                    }
                    S0 = fmaf(valid, x0[u], S0);
                }
            }

            _Float16* Fr = Fl + (size_t)nsub * LDK;
            #pragma unroll
            for (int j = 0; j < JS; ++j)
                Fr[(ihalf + j) * 32 + m] = (_Float16)(Sacc[j] * iv);
            if (lane < CIN)
                Fr[32 * CIN + lane] = (_Float16)(S0 * iv);
            else if (lane < 2 * CIN)
                Fr[32 * CIN + lane] = (_Float16)xin[(size_t)d * CIN + (lane - CIN)];
        }
    }
    __syncthreads();

    // ---- Phase B: 8-way K-split MFMA ----
    const int o16 = lane & 15, g = lane >> 4;

    const _Float16* Arow = Fl + (size_t)o16 * LDK + g * 4;
    const _Float16* B0 = Wt + (size_t)o16 * K + g * 4;
    const _Float16* B1 = Wt + (size_t)(o16 + 16) * K + g * 4;

    f32x4 acc0 = {0.f, 0.f, 0.f, 0.f};
    f32x4 acc1 = {0.f, 0.f, 0.f, 0.f};

    const int sb = (steps * w) >> 3;
    const int se = (steps * (w + 1)) >> 3;
    #pragma unroll 2
    for (int s = sb; s < se; ++s) {
        const int k0 = s * 32;
        f16x4 alo = *(const f16x4*)(Arow + k0);
        f16x4 ahi = *(const f16x4*)(Arow + k0 + 16);
        f16x4 b0l = *(const f16x4*)(B0 + k0);
        f16x4 b0h = *(const f16x4*)(B0 + k0 + 16);
        f16x4 b1l = *(const f16x4*)(B1 + k0);
        f16x4 b1h = *(const f16x4*)(B1 + k0 + 16);
        f16x8 a, bb0, bb1;
        #pragma unroll
        for (int j = 0; j < 4; ++j) {
            a[j] = alo[j];  a[j + 4] = ahi[j];
            bb0[j] = b0l[j]; bb0[j + 4] = b0h[j];
            bb1[j] = b1l[j]; bb1[j + 4] = b1h[j];
        }
        acc0 = __builtin_amdgcn_mfma_f32_16x16x32_f16(a, bb0, acc0, 0, 0, 0);
        acc1 = __builtin_amdgcn_mfma_f32_16x16x32_f16(a, bb1, acc1, 0, 0, 0);
    }

    if (w > 0) {
        float* rw = red + (w - 1) * 512;
        #pragma unroll
        for (int r = 0; r < 4; ++r) {
            rw[(g * 4 + r) * 32 + o16]      = acc0[r];
            rw[(g * 4 + r) * 32 + 16 + o16] = acc1[r];
        }
    }
    __syncthreads();
    if (w == 0) {
        #pragma unroll
        for (int r = 0; r < 4; ++r) {
            const int ro = (g * 4 + r) * 32 + o16;
            #pragma unroll
            for (int p = 0; p < 7; ++p) {
                acc0[r] += red[p * 512 + ro];
                acc1[r] += red[p * 512 + ro + 16];
            }
        }
        const float bb0 = bias[o16], bb1 = bias[o16 + 16];
        const int nrow = n0 + g * 4;
        if (!DECODE) {
            #pragma unroll
            for (int r = 0; r < 4; ++r) {
                outp[(size_t)(nrow + r) * 32 + o16]      = silu_f(acc0[r] + bb0);
                outp[(size_t)(nrow + r) * 32 + 16 + o16] = silu_f(acc1[r] + bb1);
            }
        } else {
            const float w0 = dw[o16], w1v = dw[o16 + 16];
            const float dbv = db[0];
            #pragma unroll
            for (int r = 0; r < 4; ++r) {
                float p = silu_f(acc0[r] + bb0) * w0 + silu_f(acc1[r] + bb1) * w1v;
                p += __shfl_xor(p, 1);
                p += __shfl_xor(p, 2);
                p += __shfl_xor(p, 4);
                p += __shfl_xor(p, 8);
                if (o16 == 0) outp[nrow + r] = p + dbv;
            }
        }
    }
}

// ---------------- launch ----------------

extern "C" void kernel_launch(void* const* d_in, const int* in_sizes, int n_in,
                              void* d_out, int out_size, void* d_ws, size_t ws_size,
                              hipStream_t stream) {
    const float* x      = (const float*)d_in[0];
    const int*   ei     = (const int*)d_in[1];
    const float* ew     = (const float*)d_in[2];
    const float* en1_w1 = (const float*)d_in[3];
    const float* en1_b1 = (const float*)d_in[4];
    const float* en1_w2 = (const float*)d_in[5];
    const float* en1_b2 = (const float*)d_in[6];
    const float* root1  = (const float*)d_in[7];
    const float* bias1  = (const float*)d_in[8];
    const float* en2_w1 = (const float*)d_in[9];
    const float* en2_b1 = (const float*)d_in[10];
    const float* en2_w2 = (const float*)d_in[11];
    const float* en2_b2 = (const float*)d_in[12];
    const float* root2  = (const float*)d_in[13];
    const float* bias2  = (const float*)d_in[14];
    const float* dec_w  = (const float*)d_in[15];
    const float* dec_b  = (const float*)d_in[16];
    float* out = (float*)d_out;
    (void)in_sizes; (void)n_in; (void)out_size; (void)ws_size;

    char* wp = (char*)d_ws;
    auto alloc = [&](size_t bytes) {
        char* p = wp;
        wp += (bytes + 255) & ~(size_t)255;
        return p;
    };
    int*      cnt  = (int*)alloc((size_t)NN * 4);
    int*      off  = (int*)alloc((size_t)(NN + 1) * 4);
    int*      cur  = (int*)alloc((size_t)NN * 4);
    float*    invc = (float*)alloc((size_t)NN * 4);
    int*      ssrc = (int*)alloc((size_t)EE * 4);
    float*    sew  = (float*)alloc((size_t)EE * 4);
    float*    h1   = (float*)alloc((size_t)NN * 32 * 4);
    _Float16* Wt1  = (_Float16*)alloc((size_t)17408 * 2);
    _Float16* Wt2  = (_Float16*)alloc((size_t)34816 * 2);

    hipMemsetAsync(cnt, 0, (size_t)NN * 4, stream);

    count_kernel<<<(EE + 255) / 256, 256, 0, stream>>>(ei, cnt);
    scan_kernel<<<1, 1024, 0, stream>>>(cnt, off, cur, invc);
    scatter_kernel<<<(EE + 255) / 256, 256, 0, stream>>>(ei, ew, cur, ssrc, sew);
    build_wt<<<(52224 + 255) / 256, 256, 0, stream>>>(en1_w2, en1_b2, root1,
                                                      en2_w2, en2_b2, root2, Wt1, Wt2);

    fused_layer<16, false><<<NN / 16, 512, 0, stream>>>(
        x, ssrc, sew, off, invc, en1_w1, en1_b1, Wt1, bias1, h1, nullptr, nullptr);
    fused_layer<32, true><<<NN / 16, 512, 0, stream>>>(
        h1, ssrc, sew, off, invc, en2_w1, en2_b1, Wt2, bias2, out, dec_w, dec_b);
}

// Round 9
// 136.746 us; speedup vs baseline: 1.2205x; 1.2186x over previous
//
#include <hip/hip_runtime.h>
#include <hip/hip_bf16.h>

#define NN 20000
#define EE 160000
#define HH 32
#define MIDD 32

typedef _Float16 f16x4 __attribute__((ext_vector_type(4)));
typedef _Float16 f16x8 __attribute__((ext_vector_type(8)));
typedef float f32x4 __attribute__((ext_vector_type(4)));

__device__ __forceinline__ float silu_f(float v) {
    return __fdividef(v, 1.0f + __expf(-v));
}

// async global->LDS, 4B per lane; LDS dest = wave-uniform base + 4*lane.
__device__ __forceinline__ void gload_lds_b32(const void* gsrc, void* ldst) {
    __builtin_amdgcn_global_load_lds(
        (const __attribute__((address_space(1))) void*)gsrc,
        (__attribute__((address_space(3))) void*)ldst, 4, 0, 0);
}

// ---------------- prep kernels ----------------

__global__ void count_kernel(const int* __restrict__ ei, int* __restrict__ cnt) {
    int e = blockIdx.x * 256 + threadIdx.x;
    if (e < EE) atomicAdd(&cnt[ei[EE + e]], 1);
}

__global__ void scan_kernel(const int* __restrict__ cnt, int* __restrict__ off,
                            int* __restrict__ cur, float* __restrict__ invc) {
    __shared__ int tot[1024];
    const int t = threadIdx.x;
    const int CH = 20;
    int base = t * CH;
    int loc[CH];
    int s = 0;
    #pragma unroll
    for (int r = 0; r < CH; ++r) {
        int idx = base + r;
        int c = (idx < NN) ? cnt[idx] : 0;
        loc[r] = s;
        s += c;
    }
    tot[t] = s;
    __syncthreads();
    for (int d = 1; d < 1024; d <<= 1) {
        int u = (t >= d) ? tot[t - d] : 0;
        __syncthreads();
        tot[t] += u;
        __syncthreads();
    }
    int basesum = (t == 0) ? 0 : tot[t - 1];
    #pragma unroll
    for (int r = 0; r < CH; ++r) {
        int idx = base + r;
        if (idx < NN) {
            int o = basesum + loc[r];
            off[idx] = o;
            cur[idx] = o;
            invc[idx] = 1.0f / fmaxf((float)cnt[idx], 1.0f);
        }
    }
    if (t == 0) off[NN] = EE;
}

__global__ void scatter_kernel(const int* __restrict__ ei, const float* __restrict__ ewt,
                               int* __restrict__ cur,
                               int* __restrict__ ssrc, float* __restrict__ sew) {
    int e = blockIdx.x * 256 + threadIdx.x;
    if (e < EE) {
        int d = ei[EE + e];
        int pos = atomicAdd(&cur[d], 1);
        ssrc[pos] = ei[e];
        sew[pos] = ewt[e];
    }
}

// Wt[o][k] fp16 transposed weights. S-part k = 32*i + m  ->  w2[m*(CIN*32)+i*32+o];
// tail1 k = 32*CIN + t -> b2[t*32+o]; tail2 k = 33*CIN + t -> root[t*32+o].
__global__ void build_wt(const float* __restrict__ w2a, const float* __restrict__ b2a,
                         const float* __restrict__ ra,
                         const float* __restrict__ w2b, const float* __restrict__ b2b,
                         const float* __restrict__ rb,
                         _Float16* __restrict__ Wt1, _Float16* __restrict__ Wt2) {
    int idx = blockIdx.x * 256 + threadIdx.x;
    if (idx < 17408) {                       // 32 * 544 (CIN=16)
        int o = idx / 544, k = idx % 544;
        float v;
        if (k < 512) {
            int m = k & 31, i = k >> 5;
            v = w2a[m * 512 + i * 32 + o];
        } else if (k < 528) {
            v = b2a[(k - 512) * 32 + o];
        } else {
            v = ra[(k - 528) * 32 + o];
        }
        Wt1[o * 544 + k] = (_Float16)v;
    } else if (idx < 52224) {                // + 32 * 1088 (CIN=32)
        int j = idx - 17408;
        int o = j / 1088, k = j % 1088;
        float v;
        if (k < 1024) {
            int m = k & 31, i = k >> 5;
            v = w2b[m * 1024 + i * 32 + o];
        } else if (k < 1056) {
            v = b2b[(k - 1024) * 32 + o];
        } else {
            v = rb[(k - 1056) * 32 + o];
        }
        Wt2[o * 1088 + k] = (_Float16)v;
    }
}

// ---------------- fused layer: async-staged edges -> LDS -> MFMA -----------
// Block = 512 thr (8 waves), 16 nodes, contiguous CSR edge range [E0,E1).
// A1: waves 0/1 stage ssrc/sew slice to LDS (async, coalesced).  barrier.
// A2: all waves issue async row gathers: one global_load_lds per 64/CIN rows
//     (per-lane global addr = x + sn*CIN + elem; LDS dest lane*4 = row-major).
//     barrier (drains vmcnt -> rows resident).
// A3: wave w computes nodes 2w,2w+1 reading rows/weights from LDS (ds-latency),
//     writes F rows (f16) to Fl. Edges beyond CAP (prob ~1e-5) use the old
//     global-gather fallback.  barrier.
// B:  verified 8-way K-split MFMA; partials to red[] (aliases staging pool —
//     lifetimes separated by the A3/B barrier); wave 0 reduces + epilogue.

template <int CIN, bool DECODE>
__global__ __launch_bounds__(512, 4) void fused_layer(
    const float* __restrict__ xin, const int* __restrict__ ssrc,
    const float* __restrict__ sew, const int* __restrict__ off,
    const float* __restrict__ invc, const float* __restrict__ w1,
    const float* __restrict__ b1, const _Float16* __restrict__ Wt,
    const float* __restrict__ bias, float* __restrict__ outp,
    const float* __restrict__ dw, const float* __restrict__ db) {
    constexpr int K = 34 * CIN;              // 544 or 1088
    constexpr int LDK = K + 4;
    constexpr int JS = (32 * CIN) / 64;      // 8 or 16
    constexpr int NQ = JS / 4;               // 2 or 4
    constexpr int steps = K / 32;            // 17 or 34
    constexpr int CAP = 256;                 // staged-edge capacity
    constexpr int RPG = 64 / CIN;            // rows per staging instr: 4 or 2

    extern __shared__ char smem[];
    _Float16* Fl = (_Float16*)smem;                          // 16*LDK f16
    float* pool = (float*)(smem + (size_t)16 * LDK * 2);
    int*   Is = (int*)pool;                                  // [CAP]
    float* Es = pool + CAP;                                  // [CAP]
    float* Xs = pool + 2 * CAP;                              // [CAP*CIN]
    float* red = pool;                                       // phase-B alias

    const int t = threadIdx.x;
    const int n0 = blockIdx.x * 16;
    const int lane = t & 63, w = t >> 6;     // 8 waves

    const int E0 = off[n0];
    const int E1 = off[n0 + 16];
    const int L = E1 - E0;
    const int Lc = (L < CAP) ? L : CAP;

    // ---- A1: stage edge indices + weights ----
    if (w == 0) {
        for (int c = 0; c < Lc; c += 64) {
            int idx = c + lane; idx = (idx < L - 1) ? idx : (L - 1);
            gload_lds_b32(ssrc + E0 + idx, Is + c);
        }
    } else if (w == 1) {
        for (int c = 0; c < Lc; c += 64) {
            int idx = c + lane; idx = (idx < L - 1) ? idx : (L - 1);
            gload_lds_b32(sew + E0 + idx, Es + c);
        }
    }
    __syncthreads();

    // ---- A2: async row gathers ----
    {
        const int G = (Lc + RPG - 1) / RPG;
        const int er = lane / CIN;            // row within group
        const int ec = lane & (CIN - 1);      // element
        for (int p = w; p < G; p += 8) {
            int el = p * RPG + er; el = (el < Lc - 1) ? el : (Lc - 1);
            int sn = Is[el];
            gload_lds_b32(xin + (size_t)sn * CIN + ec,
                          Xs + (size_t)p * RPG * CIN);
        }
    }
    __syncthreads();

    // ---- A3: per-node accumulation from LDS ----
    {
        const int m = lane & 31;
        const int ihalf = (lane >> 5) * JS;
        const int i0 = lane & (CIN - 1);
        const float w1v = w1[m];
        const float b1v = b1[m];

        for (int c = 0; c < 2; ++c) {
            const int nsub = w * 2 + c;
            const int d = n0 + nsub;
            float Sacc[JS];
            #pragma unroll
            for (int j = 0; j < JS; ++j) Sacc[j] = 0.f;
            float S0 = 0.f;

            const int e0l = off[d] - E0, e1l = off[d + 1] - E0;
            const int eL = (e1l < Lc) ? e1l : Lc;
            const float iv = invc[d];

            #pragma unroll 2
            for (int el = e0l; el < eL; ++el) {
                const float ew = Es[el];
                const float hv = silu_f(fmaf(ew, w1v, b1v));
                const int rb = el * CIN;
                float4 xv[NQ];
                #pragma unroll
                for (int q = 0; q < NQ; ++q)
                    xv[q] = *(const float4*)&Xs[rb + ihalf + 4 * q];
                #pragma unroll
                for (int q = 0; q < NQ; ++q) {
                    Sacc[4 * q + 0] = fmaf(hv, xv[q].x, Sacc[4 * q + 0]);
                    Sacc[4 * q + 1] = fmaf(hv, xv[q].y, Sacc[4 * q + 1]);
                    Sacc[4 * q + 2] = fmaf(hv, xv[q].z, Sacc[4 * q + 2]);
                    Sacc[4 * q + 3] = fmaf(hv, xv[q].w, Sacc[4 * q + 3]);
                }
                S0 += Xs[rb + i0];
            }
            // cold overflow path (L > CAP only)
            for (int el = eL; el < e1l; ++el) {
                const int sn2 = ssrc[E0 + el];
                const float ew2 = sew[E0 + el];
                const float hv2 = silu_f(fmaf(ew2, w1v, b1v));
                const float* xrow = xin + (size_t)sn2 * CIN;
                #pragma unroll
                for (int q = 0; q < NQ; ++q) {
                    float4 xq = *(const float4*)(xrow + ihalf + 4 * q);
                    Sacc[4 * q + 0] = fmaf(hv2, xq.x, Sacc[4 * q + 0]);
                    Sacc[4 * q + 1] = fmaf(hv2, xq.y, Sacc[4 * q + 1]);
                    Sacc[4 * q + 2] = fmaf(hv2, xq.z, Sacc[4 * q + 2]);
                    Sacc[4 * q + 3] = fmaf(hv2, xq.w, Sacc[4 * q + 3]);
                }
                S0 += xrow[i0];
            }

            _Float16* Fr = Fl + (size_t)nsub * LDK;
            #pragma unroll
            for (int j = 0; j < JS; ++j)
                Fr[(ihalf + j) * 32 + m] = (_Float16)(Sacc[j] * iv);
            if (lane < CIN)
                Fr[32 * CIN + lane] = (_Float16)(S0 * iv);
            else if (lane < 2 * CIN)
                Fr[32 * CIN + lane] = (_Float16)xin[(size_t)d * CIN + (lane - CIN)];
        }
    }
    __syncthreads();

    // ---- Phase B: 8-way K-split MFMA ----
    const int o16 = lane & 15, g = lane >> 4;

    const _Float16* Arow = Fl + (size_t)o16 * LDK + g * 4;
    const _Float16* B0 = Wt + (size_t)o16 * K + g * 4;
    const _Float16* B1 = Wt + (size_t)(o16 + 16) * K + g * 4;

    f32x4 acc0 = {0.f, 0.f, 0.f, 0.f};
    f32x4 acc1 = {0.f, 0.f, 0.f, 0.f};

    const int sb = (steps * w) >> 3;
    const int se = (steps * (w + 1)) >> 3;
    #pragma unroll 2
    for (int s = sb; s < se; ++s) {
        const int k0 = s * 32;
        f16x4 alo = *(const f16x4*)(Arow + k0);
        f16x4 ahi = *(const f16x4*)(Arow + k0 + 16);
        f16x4 b0l = *(const f16x4*)(B0 + k0);
        f16x4 b0h = *(const f16x4*)(B0 + k0 + 16);
        f16x4 b1l = *(const f16x4*)(B1 + k0);
        f16x4 b1h = *(const f16x4*)(B1 + k0 + 16);
        f16x8 a, bb0, bb1;
        #pragma unroll
        for (int j = 0; j < 4; ++j) {
            a[j] = alo[j];  a[j + 4] = ahi[j];
            bb0[j] = b0l[j]; bb0[j + 4] = b0h[j];
            bb1[j] = b1l[j]; bb1[j + 4] = b1h[j];
        }
        acc0 = __builtin_amdgcn_mfma_f32_16x16x32_f16(a, bb0, acc0, 0, 0, 0);
        acc1 = __builtin_amdgcn_mfma_f32_16x16x32_f16(a, bb1, acc1, 0, 0, 0);
    }

    if (w > 0) {
        float* rw = red + (w - 1) * 512;
        #pragma unroll
        for (int r = 0; r < 4; ++r) {
            rw[(g * 4 + r) * 32 + o16]      = acc0[r];
            rw[(g * 4 + r) * 32 + 16 + o16] = acc1[r];
        }
    }
    __syncthreads();
    if (w == 0) {
        #pragma unroll
        for (int r = 0; r < 4; ++r) {
            const int ro = (g * 4 + r) * 32 + o16;
            #pragma unroll
            for (int p = 0; p < 7; ++p) {
                acc0[r] += red[p * 512 + ro];
                acc1[r] += red[p * 512 + ro + 16];
            }
        }
        const float bb0 = bias[o16], bb1 = bias[o16 + 16];
        const int nrow = n0 + g * 4;
        if (!DECODE) {
            #pragma unroll
            for (int r = 0; r < 4; ++r) {
                outp[(size_t)(nrow + r) * 32 + o16]      = silu_f(acc0[r] + bb0);
                outp[(size_t)(nrow + r) * 32 + 16 + o16] = silu_f(acc1[r] + bb1);
            }
        } else {
            const float w0 = dw[o16], w1v = dw[o16 + 16];
            const float dbv = db[0];
            #pragma unroll
            for (int r = 0; r < 4; ++r) {
                float p = silu_f(acc0[r] + bb0) * w0 + silu_f(acc1[r] + bb1) * w1v;
                p += __shfl_xor(p, 1);
                p += __shfl_xor(p, 2);
                p += __shfl_xor(p, 4);
                p += __shfl_xor(p, 8);
                if (o16 == 0) outp[nrow + r] = p + dbv;
            }
        }
    }
}

// ---------------- launch ----------------

extern "C" void kernel_launch(void* const* d_in, const int* in_sizes, int n_in,
                              void* d_out, int out_size, void* d_ws, size_t ws_size,
                              hipStream_t stream) {
    const float* x      = (const float*)d_in[0];
    const int*   ei     = (const int*)d_in[1];
    const float* ew     = (const float*)d_in[2];
    const float* en1_w1 = (const float*)d_in[3];
    const float* en1_b1 = (const float*)d_in[4];
    const float* en1_w2 = (const float*)d_in[5];
    const float* en1_b2 = (const float*)d_in[6];
    const float* root1  = (const float*)d_in[7];
    const float* bias1  = (const float*)d_in[8];
    const float* en2_w1 = (const float*)d_in[9];
    const float* en2_b1 = (const float*)d_in[10];
    const float* en2_w2 = (const float*)d_in[11];
    const float* en2_b2 = (const float*)d_in[12];
    const float* root2  = (const float*)d_in[13];
    const float* bias2  = (const float*)d_in[14];
    const float* dec_w  = (const float*)d_in[15];
    const float* dec_b  = (const float*)d_in[16];
    float* out = (float*)d_out;
    (void)in_sizes; (void)n_in; (void)out_size; (void)ws_size;

    char* wp = (char*)d_ws;
    auto alloc = [&](size_t bytes) {
        char* p = wp;
        wp += (bytes + 255) & ~(size_t)255;
        return p;
    };
    int*      cnt  = (int*)alloc((size_t)NN * 4);
    int*      off  = (int*)alloc((size_t)(NN + 1) * 4);
    int*      cur  = (int*)alloc((size_t)NN * 4);
    float*    invc = (float*)alloc((size_t)NN * 4);
    int*      ssrc = (int*)alloc((size_t)EE * 4);
    float*    sew  = (float*)alloc((size_t)EE * 4);
    float*    h1   = (float*)alloc((size_t)NN * 32 * 4);
    _Float16* Wt1  = (_Float16*)alloc((size_t)17408 * 2);
    _Float16* Wt2  = (_Float16*)alloc((size_t)34816 * 2);

    hipMemsetAsync(cnt, 0, (size_t)NN * 4, stream);

    count_kernel<<<(EE + 255) / 256, 256, 0, stream>>>(ei, cnt);
    scan_kernel<<<1, 1024, 0, stream>>>(cnt, off, cur, invc);
    scatter_kernel<<<(EE + 255) / 256, 256, 0, stream>>>(ei, ew, cur, ssrc, sew);
    build_wt<<<(52224 + 255) / 256, 256, 0, stream>>>(en1_w2, en1_b2, root1,
                                                      en2_w2, en2_b2, root2, Wt1, Wt2);

    auto f1 = fused_layer<16, false>;
    auto f2 = fused_layer<32, true>;
    (void)hipFuncSetAttribute((const void*)f1,
                              hipFuncAttributeMaxDynamicSharedMemorySize, 163840);
    (void)hipFuncSetAttribute((const void*)f2,
                              hipFuncAttributeMaxDynamicSharedMemorySize, 163840);

    // lds = Fl + pool;  pool = max(7*512, CAP*(2+CIN)) floats
    const size_t lds1 = (size_t)16 * (34 * 16 + 4) * 2 + (size_t)256 * 18 * 4; // 35,968
    const size_t lds2 = (size_t)16 * (34 * 32 + 4) * 2 + (size_t)256 * 34 * 4; // 69,760

    fused_layer<16, false><<<NN / 16, 512, lds1, stream>>>(
        x, ssrc, sew, off, invc, en1_w1, en1_b1, Wt1, bias1, h1, nullptr, nullptr);
    fused_layer<32, true><<<NN / 16, 512, lds2, stream>>>(
        h1, ssrc, sew, off, invc, en2_w1, en2_b1, Wt2, bias2, out, dec_w, dec_b);
}

// Round 10
// 101.987 us; speedup vs baseline: 1.6365x; 1.3408x over previous
//
#include <hip/hip_runtime.h>
#include <hip/hip_bf16.h>

#define NN 20000
#define EE 160000
#define HH 32
#define MIDD 32

typedef _Float16 f16x4 __attribute__((ext_vector_type(4)));
typedef _Float16 f16x8 __attribute__((ext_vector_type(8)));
typedef float f32x4 __attribute__((ext_vector_type(4)));

__device__ __forceinline__ float silu_f(float v) {
    return __fdividef(v, 1.0f + __expf(-v));
}

// async global->LDS, 4B per lane; LDS dest = wave-uniform base + 4*lane.
__device__ __forceinline__ void gload_lds_b32(const void* gsrc, void* ldst) {
    __builtin_amdgcn_global_load_lds(
        (const __attribute__((address_space(1))) void*)gsrc,
        (__attribute__((address_space(3))) void*)ldst, 4, 0, 0);
}

// ---------------- prep kernels ----------------

__global__ void count_kernel(const int* __restrict__ ei, int* __restrict__ cnt) {
    int e = blockIdx.x * 256 + threadIdx.x;
    if (e < EE) atomicAdd(&cnt[ei[EE + e]], 1);
}

// Vectorized single-block scan: thread t owns cnt[20t..20t+20) (5x int4 loads),
// wave-shuffle inclusive scan of thread sums, 16 wave totals through LDS
// (1 barrier), 5x int4/float4 stores for off/cur/invc.
__global__ __launch_bounds__(1024) void scan_kernel(
    const int* __restrict__ cnt, int* __restrict__ off,
    int* __restrict__ cur, float* __restrict__ invc) {
    const int t = threadIdx.x;
    const int base = t * 20;
    __shared__ int wtot[16];

    int c[20];
    if (base + 20 <= NN) {
        const int4* p = (const int4*)(cnt + base);
        #pragma unroll
        for (int q = 0; q < 5; ++q) *(int4*)&c[4 * q] = p[q];
    } else {
        #pragma unroll
        for (int r = 0; r < 20; ++r) {
            int idx = base + r;
            c[r] = (idx < NN) ? cnt[idx] : 0;
        }
    }

    int loc[20];
    int s = 0;
    #pragma unroll
    for (int r = 0; r < 20; ++r) { loc[r] = s; s += c[r]; }

    // wave-level inclusive scan of per-thread sums
    const int lane = t & 63, wv = t >> 6;
    int incl = s;
    #pragma unroll
    for (int d2 = 1; d2 < 64; d2 <<= 1) {
        int u = __shfl_up(incl, d2);
        if (lane >= d2) incl += u;
    }
    if (lane == 63) wtot[wv] = incl;
    __syncthreads();
    int wbase = 0;
    for (int p2 = 0; p2 < wv; ++p2) wbase += wtot[p2];   // LDS broadcast reads

    const int excl = wbase + incl - s;   // exclusive prefix of this chunk

    int o[20];
    #pragma unroll
    for (int r = 0; r < 20; ++r) o[r] = excl + loc[r];
    float iv[20];
    #pragma unroll
    for (int r = 0; r < 20; ++r) iv[r] = 1.0f / fmaxf((float)c[r], 1.0f);

    if (base + 20 <= NN) {
        #pragma unroll
        for (int q = 0; q < 5; ++q) {
            ((int4*)(off + base))[q]    = *(const int4*)&o[4 * q];
            ((int4*)(cur + base))[q]    = *(const int4*)&o[4 * q];
            ((float4*)(invc + base))[q] = *(const float4*)&iv[4 * q];
        }
    } else {
        #pragma unroll
        for (int r = 0; r < 20; ++r) {
            int idx = base + r;
            if (idx < NN) { off[idx] = o[r]; cur[idx] = o[r]; invc[idx] = iv[r]; }
        }
    }
    if (t == 0) off[NN] = EE;
}

__global__ void scatter_kernel(const int* __restrict__ ei, const float* __restrict__ ewt,
                               int* __restrict__ cur,
                               int* __restrict__ ssrc, float* __restrict__ sew) {
    int e = blockIdx.x * 256 + threadIdx.x;
    if (e < EE) {
        int d = ei[EE + e];
        int pos = atomicAdd(&cur[d], 1);
        ssrc[pos] = ei[e];
        sew[pos] = ewt[e];
    }
}

// Wt[o][k] fp16 transposed weights. S-part k = 32*i + m  ->  w2[m*(CIN*32)+i*32+o];
// tail1 k = 32*CIN + t -> b2[t*32+o]; tail2 k = 33*CIN + t -> root[t*32+o].
__global__ void build_wt(const float* __restrict__ w2a, const float* __restrict__ b2a,
                         const float* __restrict__ ra,
                         const float* __restrict__ w2b, const float* __restrict__ b2b,
                         const float* __restrict__ rb,
                         _Float16* __restrict__ Wt1, _Float16* __restrict__ Wt2) {
    int idx = blockIdx.x * 256 + threadIdx.x;
    if (idx < 17408) {                       // 32 * 544 (CIN=16)
        int o = idx / 544, k = idx % 544;
        float v;
        if (k < 512) {
            int m = k & 31, i = k >> 5;
            v = w2a[m * 512 + i * 32 + o];
        } else if (k < 528) {
            v = b2a[(k - 512) * 32 + o];
        } else {
            v = ra[(k - 528) * 32 + o];
        }
        Wt1[o * 544 + k] = (_Float16)v;
    } else if (idx < 52224) {                // + 32 * 1088 (CIN=32)
        int j = idx - 17408;
        int o = j / 1088, k = j % 1088;
        float v;
        if (k < 1024) {
            int m = k & 31, i = k >> 5;
            v = w2b[m * 1024 + i * 32 + o];
        } else if (k < 1056) {
            v = b2b[(k - 1024) * 32 + o];
        } else {
            v = rb[(k - 1056) * 32 + o];
        }
        Wt2[o * 1088 + k] = (_Float16)v;
    }
}

// ---------------- fused layer: async-staged edges -> LDS -> MFMA -----------
// (structure verified in round 9; unchanged)

template <int CIN, bool DECODE>
__global__ __launch_bounds__(512, 4) void fused_layer(
    const float* __restrict__ xin, const int* __restrict__ ssrc,
    const float* __restrict__ sew, const int* __restrict__ off,
    const float* __restrict__ invc, const float* __restrict__ w1,
    const float* __restrict__ b1, const _Float16* __restrict__ Wt,
    const float* __restrict__ bias, float* __restrict__ outp,
    const float* __restrict__ dw, const float* __restrict__ db) {
    constexpr int K = 34 * CIN;              // 544 or 1088
    constexpr int LDK = K + 4;
    constexpr int JS = (32 * CIN) / 64;      // 8 or 16
    constexpr int NQ = JS / 4;               // 2 or 4
    constexpr int steps = K / 32;            // 17 or 34
    constexpr int CAP = 256;                 // staged-edge capacity
    constexpr int RPG = 64 / CIN;            // rows per staging instr: 4 or 2

    extern __shared__ char smem[];
    _Float16* Fl = (_Float16*)smem;                          // 16*LDK f16
    float* pool = (float*)(smem + (size_t)16 * LDK * 2);
    int*   Is = (int*)pool;                                  // [CAP]
    float* Es = pool + CAP;                                  // [CAP]
    float* Xs = pool + 2 * CAP;                              // [CAP*CIN]
    float* red = pool;                                       // phase-B alias

    const int t = threadIdx.x;
    const int n0 = blockIdx.x * 16;
    const int lane = t & 63, w = t >> 6;     // 8 waves

    const int E0 = off[n0];
    const int E1 = off[n0 + 16];
    const int L = E1 - E0;
    const int Lc = (L < CAP) ? L : CAP;

    // ---- A1: stage edge indices + weights ----
    if (w == 0) {
        for (int c = 0; c < Lc; c += 64) {
            int idx = c + lane; idx = (idx < L - 1) ? idx : (L - 1);
            gload_lds_b32(ssrc + E0 + idx, Is + c);
        }
    } else if (w == 1) {
        for (int c = 0; c < Lc; c += 64) {
            int idx = c + lane; idx = (idx < L - 1) ? idx : (L - 1);
            gload_lds_b32(sew + E0 + idx, Es + c);
        }
    }
    __syncthreads();

    // ---- A2: async row gathers ----
    {
        const int G = (Lc + RPG - 1) / RPG;
        const int er = lane / CIN;            // row within group
        const int ec = lane & (CIN - 1);      // element
        for (int p = w; p < G; p += 8) {
            int el = p * RPG + er; el = (el < Lc - 1) ? el : (Lc - 1);
            int sn = Is[el];
            gload_lds_b32(xin + (size_t)sn * CIN + ec,
                          Xs + (size_t)p * RPG * CIN);
        }
    }
    __syncthreads();

    // ---- A3: per-node accumulation from LDS ----
    {
        const int m = lane & 31;
        const int ihalf = (lane >> 5) * JS;
        const int i0 = lane & (CIN - 1);
        const float w1v = w1[m];
        const float b1v = b1[m];

        for (int c = 0; c < 2; ++c) {
            const int nsub = w * 2 + c;
            const int d = n0 + nsub;
            float Sacc[JS];
            #pragma unroll
            for (int j = 0; j < JS; ++j) Sacc[j] = 0.f;
            float S0 = 0.f;

            const int e0l = off[d] - E0, e1l = off[d + 1] - E0;
            const int eL = (e1l < Lc) ? e1l : Lc;
            const float iv = invc[d];

            #pragma unroll 2
            for (int el = e0l; el < eL; ++el) {
                const float ew = Es[el];
                const float hv = silu_f(fmaf(ew, w1v, b1v));
                const int rb = el * CIN;
                float4 xv[NQ];
                #pragma unroll
                for (int q = 0; q < NQ; ++q)
                    xv[q] = *(const float4*)&Xs[rb + ihalf + 4 * q];
                #pragma unroll
                for (int q = 0; q < NQ; ++q) {
                    Sacc[4 * q + 0] = fmaf(hv, xv[q].x, Sacc[4 * q + 0]);
                    Sacc[4 * q + 1] = fmaf(hv, xv[q].y, Sacc[4 * q + 1]);
                    Sacc[4 * q + 2] = fmaf(hv, xv[q].z, Sacc[4 * q + 2]);
                    Sacc[4 * q + 3] = fmaf(hv, xv[q].w, Sacc[4 * q + 3]);
                }
                S0 += Xs[rb + i0];
            }
            // cold overflow path (L > CAP only)
            for (int el = eL; el < e1l; ++el) {
                const int sn2 = ssrc[E0 + el];
                const float ew2 = sew[E0 + el];
                const float hv2 = silu_f(fmaf(ew2, w1v, b1v));
                const float* xrow = xin + (size_t)sn2 * CIN;
                #pragma unroll
                for (int q = 0; q < NQ; ++q) {
                    float4 xq = *(const float4*)(xrow + ihalf + 4 * q);
                    Sacc[4 * q + 0] = fmaf(hv2, xq.x, Sacc[4 * q + 0]);
                    Sacc[4 * q + 1] = fmaf(hv2, xq.y, Sacc[4 * q + 1]);
                    Sacc[4 * q + 2] = fmaf(hv2, xq.z, Sacc[4 * q + 2]);
                    Sacc[4 * q + 3] = fmaf(hv2, xq.w, Sacc[4 * q + 3]);
                }
                S0 += xrow[i0];
            }

            _Float16* Fr = Fl + (size_t)nsub * LDK;
            #pragma unroll
            for (int j = 0; j < JS; ++j)
                Fr[(ihalf + j) * 32 + m] = (_Float16)(Sacc[j] * iv);
            if (lane < CIN)
                Fr[32 * CIN + lane] = (_Float16)(S0 * iv);
            else if (lane < 2 * CIN)
                Fr[32 * CIN + lane] = (_Float16)xin[(size_t)d * CIN + (lane - CIN)];
        }
    }
    __syncthreads();

    // ---- Phase B: 8-way K-split MFMA ----
    const int o16 = lane & 15, g = lane >> 4;

    const _Float16* Arow = Fl + (size_t)o16 * LDK + g * 4;
    const _Float16* B0 = Wt + (size_t)o16 * K + g * 4;
    const _Float16* B1 = Wt + (size_t)(o16 + 16) * K + g * 4;

    f32x4 acc0 = {0.f, 0.f, 0.f, 0.f};
    f32x4 acc1 = {0.f, 0.f, 0.f, 0.f};

    const int sb = (steps * w) >> 3;
    const int se = (steps * (w + 1)) >> 3;
    #pragma unroll 2
    for (int s = sb; s < se; ++s) {
        const int k0 = s * 32;
        f16x4 alo = *(const f16x4*)(Arow + k0);
        f16x4 ahi = *(const f16x4*)(Arow + k0 + 16);
        f16x4 b0l = *(const f16x4*)(B0 + k0);
        f16x4 b0h = *(const f16x4*)(B0 + k0 + 16);
        f16x4 b1l = *(const f16x4*)(B1 + k0);
        f16x4 b1h = *(const f16x4*)(B1 + k0 + 16);
        f16x8 a, bb0, bb1;
        #pragma unroll
        for (int j = 0; j < 4; ++j) {
            a[j] = alo[j];  a[j + 4] = ahi[j];
            bb0[j] = b0l[j]; bb0[j + 4] = b0h[j];
            bb1[j] = b1l[j]; bb1[j + 4] = b1h[j];
        }
        acc0 = __builtin_amdgcn_mfma_f32_16x16x32_f16(a, bb0, acc0, 0, 0, 0);
        acc1 = __builtin_amdgcn_mfma_f32_16x16x32_f16(a, bb1, acc1, 0, 0, 0);
    }

    if (w > 0) {
        float* rw = red + (w - 1) * 512;
        #pragma unroll
        for (int r = 0; r < 4; ++r) {
            rw[(g * 4 + r) * 32 + o16]      = acc0[r];
            rw[(g * 4 + r) * 32 + 16 + o16] = acc1[r];
        }
    }
    __syncthreads();
    if (w == 0) {
        #pragma unroll
        for (int r = 0; r < 4; ++r) {
            const int ro = (g * 4 + r) * 32 + o16;
            #pragma unroll
            for (int p = 0; p < 7; ++p) {
                acc0[r] += red[p * 512 + ro];
                acc1[r] += red[p * 512 + ro + 16];
            }
        }
        const float bb0 = bias[o16], bb1 = bias[o16 + 16];
        const int nrow = n0 + g * 4;
        if (!DECODE) {
            #pragma unroll
            for (int r = 0; r < 4; ++r) {
                outp[(size_t)(nrow + r) * 32 + o16]      = silu_f(acc0[r] + bb0);
                outp[(size_t)(nrow + r) * 32 + 16 + o16] = silu_f(acc1[r] + bb1);
            }
        } else {
            const float w0 = dw[o16], w1v = dw[o16 + 16];
            const float dbv = db[0];
            #pragma unroll
            for (int r = 0; r < 4; ++r) {
                float p = silu_f(acc0[r] + bb0) * w0 + silu_f(acc1[r] + bb1) * w1v;
                p += __shfl_xor(p, 1);
                p += __shfl_xor(p, 2);
                p += __shfl_xor(p, 4);
                p += __shfl_xor(p, 8);
                if (o16 == 0) outp[nrow + r] = p + dbv;
            }
        }
    }
}

// ---------------- launch ----------------

extern "C" void kernel_launch(void* const* d_in, const int* in_sizes, int n_in,
                              void* d_out, int out_size, void* d_ws, size_t ws_size,
                              hipStream_t stream) {
    const float* x      = (const float*)d_in[0];
    const int*   ei     = (const int*)d_in[1];
    const float* ew     = (const float*)d_in[2];
    const float* en1_w1 = (const float*)d_in[3];
    const float* en1_b1 = (const float*)d_in[4];
    const float* en1_w2 = (const float*)d_in[5];
    const float* en1_b2 = (const float*)d_in[6];
    const float* root1  = (const float*)d_in[7];
    const float* bias1  = (const float*)d_in[8];
    const float* en2_w1 = (const float*)d_in[9];
    const float* en2_b1 = (const float*)d_in[10];
    const float* en2_w2 = (const float*)d_in[11];
    const float* en2_b2 = (const float*)d_in[12];
    const float* root2  = (const float*)d_in[13];
    const float* bias2  = (const float*)d_in[14];
    const float* dec_w  = (const float*)d_in[15];
    const float* dec_b  = (const float*)d_in[16];
    float* out = (float*)d_out;
    (void)in_sizes; (void)n_in; (void)out_size; (void)ws_size;

    char* wp = (char*)d_ws;
    auto alloc = [&](size_t bytes) {
        char* p = wp;
        wp += (bytes + 255) & ~(size_t)255;
        return p;
    };
    int*      cnt  = (int*)alloc((size_t)NN * 4);
    int*      off  = (int*)alloc((size_t)(NN + 1) * 4);
    int*      cur  = (int*)alloc((size_t)NN * 4);
    float*    invc = (float*)alloc((size_t)NN * 4);
    int*      ssrc = (int*)alloc((size_t)EE * 4);
    float*    sew  = (float*)alloc((size_t)EE * 4);
    float*    h1   = (float*)alloc((size_t)NN * 32 * 4);
    _Float16* Wt1  = (_Float16*)alloc((size_t)17408 * 2);
    _Float16* Wt2  = (_Float16*)alloc((size_t)34816 * 2);

    hipMemsetAsync(cnt, 0, (size_t)NN * 4, stream);

    count_kernel<<<(EE + 255) / 256, 256, 0, stream>>>(ei, cnt);
    scan_kernel<<<1, 1024, 0, stream>>>(cnt, off, cur, invc);
    scatter_kernel<<<(EE + 255) / 256, 256, 0, stream>>>(ei, ew, cur, ssrc, sew);
    build_wt<<<(52224 + 255) / 256, 256, 0, stream>>>(en1_w2, en1_b2, root1,
                                                      en2_w2, en2_b2, root2, Wt1, Wt2);

    auto f1 = fused_layer<16, false>;
    auto f2 = fused_layer<32, true>;
    (void)hipFuncSetAttribute((const void*)f1,
                              hipFuncAttributeMaxDynamicSharedMemorySize, 163840);
    (void)hipFuncSetAttribute((const void*)f2,
                              hipFuncAttributeMaxDynamicSharedMemorySize, 163840);

    // lds = Fl + pool;  pool = max(7*512, CAP*(2+CIN)) floats
    const size_t lds1 = (size_t)16 * (34 * 16 + 4) * 2 + (size_t)256 * 18 * 4; // 35,968
    const size_t lds2 = (size_t)16 * (34 * 32 + 4) * 2 + (size_t)256 * 34 * 4; // 69,760

    fused_layer<16, false><<<NN / 16, 512, lds1, stream>>>(
        x, ssrc, sew, off, invc, en1_w1, en1_b1, Wt1, bias1, h1, nullptr, nullptr);
    fused_layer<32, true><<<NN / 16, 512, lds2, stream>>>(
        h1, ssrc, sew, off, invc, en2_w1, en2_b1, Wt2, bias2, out, dec_w, dec_b);
}